// Round 1
// baseline (476.951 us; speedup 1.0000x reference)
//
#include <hip/hip_runtime.h>
#include <hip/hip_bf16.h>
#include <hip/hip_fp16.h>

#define N_NODES 200000
#define N_EDGES 500000
#define F_IN    165
#define HID     256
#define SX      192   // padded f16 row stride (24 half8 segs, 16B-aligned rows)
#define NB      782   // ceil(N_NODES/256)

typedef float    floatx4 __attribute__((ext_vector_type(4)));
typedef float    floatx4a __attribute__((ext_vector_type(4), aligned(16)));
typedef float    float4u __attribute__((ext_vector_type(4), aligned(4)));
typedef _Float16 half8   __attribute__((ext_vector_type(8)));

// ---------- K_A: fused cast_x + dst-degree histogram + bfrag pack ----------
// grid = N*24/256 = 18750 blocks; every thread does one xh seg; low-gid
// threads additionally do one hist edge; gids [1M,1M+12288) pack one bfrag elem.
__global__ void prep_kernel(const float* __restrict__ x, half8* __restrict__ xh8,
                            const int* __restrict__ ei, int* __restrict__ degi,
                            const float* __restrict__ w1l, const float* __restrict__ w1r,
                            _Float16* __restrict__ bfrag) {
    int idx = blockIdx.x * blockDim.x + threadIdx.x;   // < N*24 exactly
    {   // ---- cast x (f32, stride 165) -> xh (f16 half8 segs, stride 24) ----
        int row = idx / 24;
        int p = idx - row * 24;
        int f0 = p * 8;
        const float* px = x + (long)row * F_IN + f0;
        half8 r;
        if (f0 + 8 <= F_IN) {
            float4u lo = *(const float4u*)px;
            float4u hi = *(const float4u*)(px + 4);
#pragma unroll
            for (int q = 0; q < 4; ++q) r[q] = (_Float16)lo[q];
#pragma unroll
            for (int q = 0; q < 4; ++q) r[4 + q] = (_Float16)hi[q];
        } else {
#pragma unroll
            for (int q = 0; q < 8; ++q)
                r[q] = (f0 + q < F_IN) ? (_Float16)px[q] : (_Float16)0.0f;
        }
        xh8[idx] = r;
    }
    // ---- histogram ----
    if (idx < N_EDGES) atomicAdd(&degi[ei[N_EDGES + idx]], 1);
    // ---- pack [w1_l | w1_r] (f16) into MFMA B-fragment order ----
    int gid = idx - (1 << 20);
    if ((unsigned)gid < (unsigned)(12 * 16 * 64)) {
        int lane = gid & 63;
        int j = (gid >> 6) & 15;
        int c = gid >> 10;
        int quad = lane >> 4, n = lane & 15;
        const float* w = (c < 6) ? w1l : w1r;
        int kb = (c < 6 ? c : c - 6) * 32;
        int col = j * 16 + n;
        half8 r;
#pragma unroll
        for (int q = 0; q < 8; ++q) {
            int k = kb + quad * 8 + q;
            r[q] = (_Float16)((k < F_IN) ? w[k * HID + col] : 0.0f);
        }
        *(half8*)(bfrag + gid * 8) = r;
    }
}

// ---------- K_B: region allocator (replaces block_sum+scan_bsum+scan_emit) ----------
// Wave-level exclusive scan of deg + one global atomicAdd per wave. CSR region
// ORDER is nondeterministic (harmless: per-node content identical; intra-region
// order was already nondeterministic from scatter atomics). Gathers use
// e1 = e0 + degi[n] instead of row_start[n+1].
__global__ __launch_bounds__(256) void region_kernel(const int* __restrict__ degi,
                                                     int* __restrict__ row_start,
                                                     int* __restrict__ cursor,
                                                     float* __restrict__ invdeg,
                                                     int* __restrict__ gctr) {
    int i = blockIdx.x * 256 + threadIdx.x;
    int lane = threadIdx.x & 63;
    int d = (i < N_NODES) ? degi[i] : 0;
    int pre = d;
#pragma unroll
    for (int m = 1; m < 64; m <<= 1) {
        int u = __shfl_up(pre, m, 64);
        if (lane >= m) pre += u;
    }
    int base = 0;
    if (lane == 63) base = atomicAdd(gctr, pre);   // pre == wave total at lane 63
    base = __shfl(base, 63, 64);
    if (i < N_NODES) {
        int rs = base + pre - d;                   // exclusive within wave
        row_start[i] = rs;
        cursor[i] = rs;
        invdeg[i] = 1.0f / fmaxf((float)d, 1.0f);
    }
}

// ---------- K_C: bucket edges into CSR ----------
__global__ void scatter_edges_kernel(const int* __restrict__ ei,
                                     int* __restrict__ cursor,
                                     int* __restrict__ csr) {
    int e = blockIdx.x * blockDim.x + threadIdx.x;
    if (e >= N_EDGES) return;
    int s = ei[e];
    int d = ei[N_EDGES + e];
    int pos = atomicAdd(&cursor[d], 1);
    csr[pos] = s;
}

// ---------- K_D: gather-aggregate (NO atomics): aggh[n] = sum xh[src] ----------
__global__ void gather_agg_kernel(const half8* __restrict__ xh8,
                                  const int* __restrict__ row_start,
                                  const int* __restrict__ degi,
                                  const int* __restrict__ csr,
                                  half8* __restrict__ aggh8) {
    int idx = blockIdx.x * blockDim.x + threadIdx.x;   // < N*24
    int n = idx / 24;
    int p = idx - n * 24;
    int e0 = row_start[n], e1 = e0 + degi[n];
    half8 acc = {0, 0, 0, 0, 0, 0, 0, 0};
    half8 acc2 = {0, 0, 0, 0, 0, 0, 0, 0};
    int e = e0;
    for (; e + 2 <= e1; e += 2) {
        int s0 = csr[e], s1 = csr[e + 1];
        half8 v0 = xh8[(long)s0 * 24 + p];
        half8 v1 = xh8[(long)s1 * 24 + p];
        acc += v0;
        acc2 += v1;
    }
    if (e < e1) acc += xh8[(long)csr[e] * 24 + p];
    aggh8[idx] = acc + acc2;
}

// ---------- K_E: fused MFMA GEMM + invdeg + bias + relu + layer-2 projection ----------
// 2-phase software pipeline (guide T3 minimum recipe): STAGE(next pair) issued
// BEFORE compute(current pair); single "s_waitcnt vmcnt(0); s_barrier" per pair.
// vmcnt(0) (not counted) keeps correctness independent of compiler-issued loads.
// As[2] are 128x64 pair buffers (32KB); XOR-swizzled LDS slots, DMA lane-linear.
__global__ __launch_bounds__(512, 2) void gemm_fused_kernel(
        const _Float16* __restrict__ xh, const _Float16* __restrict__ aggh,
        const float* __restrict__ invdeg, const _Float16* __restrict__ bfrag,
        const float* __restrict__ b1,
        const float* __restrict__ w2l, const float* __restrict__ w2r,
        float* __restrict__ tl, float* __restrict__ tr) {
    __shared__ __attribute__((aligned(16))) _Float16 As[2][128 * 64];  // 2 x 16KB
    __shared__ float tlr[128][4];
    const int tid = threadIdx.x;
    const int w = tid >> 6, lane = tid & 63;
    const int quad = lane >> 4, l15 = lane & 15;
    const int rowbase = blockIdx.x * 128;
    const int mrow0 = rowbase + (w & 1) * 64;
    const int rhalf = (w & 1) * 64;
    const int jbase = (w >> 1) * 4;

    ((float*)tlr)[tid] = 0.0f;   // 512 floats, one per thread

    const int srow_l = tid >> 2;
    const int sseg = (tid & 3) ^ ((srow_l >> 1) & 3);
    int srow = rowbase + srow_l;
    if (srow >= N_NODES) srow = N_NODES - 1;
    const long sgoff = (long)srow * SX + sseg * 8;

    floatx4 acc[4][4];
#pragma unroll
    for (int i = 0; i < 4; ++i)
#pragma unroll
        for (int jj = 0; jj < 4; ++jj)
            acc[i][jj] = (floatx4){0.f, 0.f, 0.f, 0.f};

    // ---- prologue: stage pair 0 into As[0], wait, barrier ----
#pragma unroll
    for (int u = 0; u < 2; ++u) {
        const int cc = u;
        const _Float16* __restrict__ src = (cc < 6) ? aggh : xh;
        const int kb = (cc < 6 ? cc : cc - 6) * 32;
        const _Float16* gp = src + sgoff + kb;
        char* dst = (char*)(&As[0][u * 128 * 32]) + (tid & ~63) * 16;
        __builtin_amdgcn_global_load_lds(
            (const __attribute__((address_space(1))) void*)gp,
            (__attribute__((address_space(3))) void*)dst, 16, 0, 0);
    }
    asm volatile("s_waitcnt vmcnt(0)" ::: "memory");
    __builtin_amdgcn_s_barrier();
    __builtin_amdgcn_sched_barrier(0);

#pragma unroll
    for (int t = 0; t < 6; ++t) {
        // ---- issue next pair's DMA (overlaps with compute below) ----
        if (t < 5) {
#pragma unroll
            for (int u = 0; u < 2; ++u) {
                const int cc = (t + 1) * 2 + u;
                const _Float16* __restrict__ src = (cc < 6) ? aggh : xh;
                const int kb = (cc < 6 ? cc : cc - 6) * 32;
                const _Float16* gp = src + sgoff + kb;
                char* dst = (char*)(&As[(t + 1) & 1][u * 128 * 32]) + (tid & ~63) * 16;
                __builtin_amdgcn_global_load_lds(
                    (const __attribute__((address_space(1))) void*)gp,
                    (__attribute__((address_space(3))) void*)dst, 16, 0, 0);
            }
        }
        // ---- compute current pair from As[t&1] ----
#pragma unroll
        for (int u = 0; u < 2; ++u) {
            const int cc = t * 2 + u;
            half8 a[4], b[4];
#pragma unroll
            for (int i = 0; i < 4; ++i) {
                int r = rhalf + i * 16 + l15;
                int slot = r * 4 + (quad ^ ((r >> 1) & 3));
                a[i] = *(const half8*)(&As[t & 1][u * 128 * 32 + slot * 8]);
            }
#pragma unroll
            for (int jj = 0; jj < 4; ++jj)
                b[jj] = *(const half8*)(bfrag + (((cc * 16) + jbase + jj) * 64 + lane) * 8);
#pragma unroll
            for (int i = 0; i < 4; ++i)
#pragma unroll
                for (int jj = 0; jj < 4; ++jj)
                    acc[i][jj] = __builtin_amdgcn_mfma_f32_16x16x32_f16(a[i], b[jj], acc[i][jj], 0, 0, 0);

            if (cc == 5) {   // agg phase done: scale accumulator rows by invdeg
#pragma unroll
                for (int i = 0; i < 4; ++i) {
                    int rb = mrow0 + i * 16 + quad * 4;
                    floatx4 iv;
                    if (rb + 3 < N_NODES) {
                        iv = *(const floatx4a*)(invdeg + rb);
                    } else {
#pragma unroll
                        for (int q = 0; q < 4; ++q)
                            iv[q] = (rb + q < N_NODES) ? invdeg[rb + q] : 0.0f;
                    }
#pragma unroll
                    for (int jj = 0; jj < 4; ++jj)
                        acc[i][jj] *= iv;
                }
            }
        }
        // ---- next pair ready + all waves done reading current pair ----
        asm volatile("s_waitcnt vmcnt(0)" ::: "memory");
        __builtin_amdgcn_s_barrier();
        __builtin_amdgcn_sched_barrier(0);
    }

    float bb[4], wl0[4], wl1[4], wr0[4], wr1[4];
#pragma unroll
    for (int jj = 0; jj < 4; ++jj) {
        int col = (w >> 1) * 64 + jj * 16 + l15;
        bb[jj]  = b1[col];
        wl0[jj] = w2l[col * 2];  wl1[jj] = w2l[col * 2 + 1];
        wr0[jj] = w2r[col * 2];  wr1[jj] = w2r[col * 2 + 1];
    }
#pragma unroll
    for (int i = 0; i < 4; ++i) {
#pragma unroll
        for (int q = 0; q < 4; ++q) {
            float s0 = 0.f, s1 = 0.f, s2 = 0.f, s3 = 0.f;
#pragma unroll
            for (int jj = 0; jj < 4; ++jj) {
                float v = fmaxf(acc[i][jj][q] + bb[jj], 0.0f);
                s0 += v * wl0[jj]; s1 += v * wl1[jj];
                s2 += v * wr0[jj]; s3 += v * wr1[jj];
            }
#pragma unroll
            for (int m = 1; m < 16; m <<= 1) {
                s0 += __shfl_xor(s0, m, 64);
                s1 += __shfl_xor(s1, m, 64);
                s2 += __shfl_xor(s2, m, 64);
                s3 += __shfl_xor(s3, m, 64);
            }
            if (l15 == 0) {
                int rl = (w & 1) * 64 + i * 16 + quad * 4 + q;
                atomicAdd(&tlr[rl][0], s0);
                atomicAdd(&tlr[rl][1], s1);
                atomicAdd(&tlr[rl][2], s2);
                atomicAdd(&tlr[rl][3], s3);
            }
        }
    }
    __syncthreads();
    if (tid < 128) {
        int row = rowbase + tid;
        if (row < N_NODES) {
            tl[row * 2 + 0] = tlr[tid][0];
            tl[row * 2 + 1] = tlr[tid][1];
            tr[row * 2 + 0] = tlr[tid][2];
            tr[row * 2 + 1] = tlr[tid][3];
        }
    }
}

// ---------- K_F: fused layer-2 gather + finalize + edge passthrough ----------
__global__ void out_kernel(const int* __restrict__ row_start,
                           const int* __restrict__ degi,
                           const int* __restrict__ csr,
                           const float* __restrict__ tl,
                           const float* __restrict__ tr,
                           const float* __restrict__ invdeg,
                           const float* __restrict__ b2,
                           const int* __restrict__ ei,
                           float* __restrict__ out) {
    int i = blockIdx.x * blockDim.x + threadIdx.x;
    if (i < N_NODES) {
        int e0 = row_start[i], e1 = e0 + degi[i];
        float a0 = 0.f, a1 = 0.f;
        for (int e = e0; e < e1; ++e) {
            int s = csr[e];
            a0 += tl[s * 2 + 0];
            a1 += tl[s * 2 + 1];
        }
        float inv = invdeg[i];
        out[i * 2 + 0] = a0 * inv + tr[i * 2 + 0] + b2[0];
        out[i * 2 + 1] = a1 * inv + tr[i * 2 + 1] + b2[1];
    }
    if (i < 2 * N_EDGES) out[2 * N_NODES + i] = (float)ei[i];
}

// ---------- workspace layout (bytes) ----------
//   0          degi      800000   (memset 0)
//   800000     row_start 800016
//   1600032    cursor    800000
//   2400032    invdeg    800000
//   3200032    csr       2000000
//   5200032    tl        1600000
//   6800032    tr        1600000
//   8400032    gctr      4        (memset 0; old bsum slot)
//   8406432    bfrag     196608
//   8610000    aggh      76800000  (f16, stride SX)
//   85410000   xh        76800000  (f16, stride SX)
extern "C" void kernel_launch(void* const* d_in, const int* in_sizes, int n_in,
                              void* d_out, int out_size, void* d_ws, size_t ws_size,
                              hipStream_t stream) {
    const float* x    = (const float*)d_in[0];
    const int*   ei   = (const int*)d_in[1];
    const float* w1_l = (const float*)d_in[2];
    const float* w1_r = (const float*)d_in[3];
    const float* b1   = (const float*)d_in[4];
    const float* w2_l = (const float*)d_in[5];
    const float* w2_r = (const float*)d_in[6];
    const float* b2   = (const float*)d_in[7];

    char* ws = (char*)d_ws;
    int*   degi      = (int*)(ws);
    int*   row_start = (int*)(ws + 800000);
    int*   cursor    = (int*)(ws + 1600032);
    float* invdeg    = (float*)(ws + 2400032);
    int*   csr       = (int*)(ws + 3200032);
    float* tl        = (float*)(ws + 5200032);
    float* tr        = (float*)(ws + 6800032);
    int*   gctr      = (int*)(ws + 8400032);
    _Float16* bfrag  = (_Float16*)(ws + 8406432);
    _Float16* aggh   = (_Float16*)(ws + 8610000);
    _Float16* xh     = (_Float16*)(ws + 85410000);

    float* out = (float*)d_out;   // f32: logits [0,400000), edges [400000,1400000)

    (void)hipMemsetAsync(degi, 0, 800000, stream);
    (void)hipMemsetAsync(gctr, 0, 4, stream);

    prep_kernel<<<(N_NODES * 24) / 256, 256, 0, stream>>>(
        x, (half8*)xh, ei, degi, w1_l, w1_r, bfrag);

    region_kernel<<<NB, 256, 0, stream>>>(degi, row_start, cursor, invdeg, gctr);
    scatter_edges_kernel<<<(N_EDGES + 255) / 256, 256, 0, stream>>>(ei, cursor, csr);

    gather_agg_kernel<<<(N_NODES * 24) / 256, 256, 0, stream>>>(
        (const half8*)xh, row_start, degi, csr, (half8*)aggh);

    gemm_fused_kernel<<<(N_NODES + 127) / 128, 512, 0, stream>>>(
        xh, aggh, invdeg, bfrag, b1, w2_l, w2_r, tl, tr);

    out_kernel<<<(2 * N_EDGES + 255) / 256, 256, 0, stream>>>(
        row_start, degi, csr, tl, tr, invdeg, b2, ei, out);
}

// Round 2
// 425.451 us; speedup vs baseline: 1.1210x; 1.1210x over previous
//
#include <hip/hip_runtime.h>
#include <hip/hip_bf16.h>
#include <hip/hip_fp16.h>

#define N_NODES 200000
#define N_EDGES 500000
#define F_IN    165
#define HID     256
#define SX      192   // padded f16 row stride (24 half8 segs, 16B-aligned rows)
#define NB      782   // ceil(N_NODES/256) scan blocks

typedef float    floatx4 __attribute__((ext_vector_type(4)));
typedef float    floatx4a __attribute__((ext_vector_type(4), aligned(16)));
typedef float    float4u __attribute__((ext_vector_type(4), aligned(4)));
typedef _Float16 half8   __attribute__((ext_vector_type(8)));

// ---------- K0: x (f32, stride 165) -> xh (f16 half8 segs, stride 24) ----------
__global__ void cast_x_kernel(const float* __restrict__ x, half8* __restrict__ xh8) {
    int idx = blockIdx.x * blockDim.x + threadIdx.x;   // < N*24
    int row = idx / 24;
    int p = idx - row * 24;
    int f0 = p * 8;
    const float* px = x + (long)row * F_IN + f0;
    half8 r;
    if (f0 + 8 <= F_IN) {
        float4u lo = *(const float4u*)px;
        float4u hi = *(const float4u*)(px + 4);
#pragma unroll
        for (int q = 0; q < 4; ++q) r[q] = (_Float16)lo[q];
#pragma unroll
        for (int q = 0; q < 4; ++q) r[4 + q] = (_Float16)hi[q];
    } else {
#pragma unroll
        for (int q = 0; q < 8; ++q)
            r[q] = (f0 + q < F_IN) ? (_Float16)px[q] : (_Float16)0.0f;
    }
    xh8[idx] = r;
}

// ---------- K1: dst-degree histogram ----------
__global__ void hist_kernel(const int* __restrict__ ei, int* __restrict__ degi) {
    int e = blockIdx.x * blockDim.x + threadIdx.x;
    if (e < N_EDGES) atomicAdd(&degi[ei[N_EDGES + e]], 1);
}

// ---------- K2a: per-block degree sums ----------
__global__ __launch_bounds__(256) void block_sum_kernel(const int* __restrict__ degi,
                                                        int* __restrict__ bsum) {
    __shared__ int sh[256];
    int t = threadIdx.x, i = blockIdx.x * 256 + t;
    sh[t] = (i < N_NODES) ? degi[i] : 0;
    __syncthreads();
#pragma unroll
    for (int off = 128; off > 0; off >>= 1) {
        if (t < off) sh[t] += sh[t + off];
        __syncthreads();
    }
    if (t == 0) bsum[blockIdx.x] = sh[0];
}

// ---------- K2b: scan the 782 block sums (1 block) ----------
__global__ __launch_bounds__(1024) void scan_bsum_kernel(const int* __restrict__ bsum,
                                                         int* __restrict__ boff,
                                                         int* __restrict__ row_start) {
    __shared__ int sh[1024];
    int t = threadIdx.x;
    int v = (t < NB) ? bsum[t] : 0;
    sh[t] = v;
    __syncthreads();
    for (int off = 1; off < 1024; off <<= 1) {
        int u = (t >= off) ? sh[t - off] : 0;
        __syncthreads();
        sh[t] += u;
        __syncthreads();
    }
    if (t < NB) boff[t] = sh[t] - v;               // exclusive
    if (t == 1023) row_start[N_NODES] = sh[1023];  // total = E
}

// ---------- K2c: emit row_start / cursor / invdeg ----------
__global__ __launch_bounds__(256) void scan_emit_kernel(const int* __restrict__ degi,
                                                        const int* __restrict__ boff,
                                                        int* __restrict__ row_start,
                                                        int* __restrict__ cursor,
                                                        float* __restrict__ invdeg) {
    __shared__ int sh[256];
    int t = threadIdx.x, i = blockIdx.x * 256 + t;
    int d = (i < N_NODES) ? degi[i] : 0;
    sh[t] = d;
    __syncthreads();
#pragma unroll
    for (int off = 1; off < 256; off <<= 1) {
        int u = (t >= off) ? sh[t - off] : 0;
        __syncthreads();
        sh[t] += u;
        __syncthreads();
    }
    if (i < N_NODES) {
        int row = boff[blockIdx.x] + sh[t] - d;    // exclusive scan value
        row_start[i] = row;
        cursor[i] = row;
        invdeg[i] = 1.0f / fmaxf((float)d, 1.0f);
    }
}

// ---------- K3: bucket edges into CSR ----------
__global__ void scatter_edges_kernel(const int* __restrict__ ei,
                                     int* __restrict__ cursor,
                                     int* __restrict__ csr) {
    int e = blockIdx.x * blockDim.x + threadIdx.x;
    if (e >= N_EDGES) return;
    int s = ei[e];
    int d = ei[N_EDGES + e];
    int pos = atomicAdd(&cursor[d], 1);
    csr[pos] = s;
}

// ---------- K4: gather-aggregate (NO atomics): aggh[n] = sum xh[src] ----------
__global__ void gather_agg_kernel(const half8* __restrict__ xh8,
                                  const int* __restrict__ row_start,
                                  const int* __restrict__ csr,
                                  half8* __restrict__ aggh8) {
    int idx = blockIdx.x * blockDim.x + threadIdx.x;   // < N*24
    int n = idx / 24;
    int p = idx - n * 24;
    int e0 = row_start[n], e1 = row_start[n + 1];
    half8 acc = {0, 0, 0, 0, 0, 0, 0, 0};
    half8 acc2 = {0, 0, 0, 0, 0, 0, 0, 0};
    int e = e0;
    for (; e + 2 <= e1; e += 2) {
        int s0 = csr[e], s1 = csr[e + 1];
        half8 v0 = xh8[(long)s0 * 24 + p];
        half8 v1 = xh8[(long)s1 * 24 + p];
        acc += v0;
        acc2 += v1;
    }
    if (e < e1) acc += xh8[(long)csr[e] * 24 + p];
    aggh8[idx] = acc + acc2;
}

// ---------- K5: pack [w1_l | w1_r] (f16) into MFMA B-fragment order ----------
__global__ void prep_bfrag_kernel(const float* __restrict__ w1l,
                                  const float* __restrict__ w1r,
                                  _Float16* __restrict__ bfrag) {
    int gid = blockIdx.x * blockDim.x + threadIdx.x;
    if (gid >= 12 * 16 * 64) return;
    int lane = gid & 63;
    int j = (gid >> 6) & 15;
    int c = gid >> 10;
    int quad = lane >> 4, n = lane & 15;
    const float* w = (c < 6) ? w1l : w1r;
    int kb = (c < 6 ? c : c - 6) * 32;
    int col = j * 16 + n;
    half8 r;
#pragma unroll
    for (int q = 0; q < 8; ++q) {
        int k = kb + quad * 8 + q;
        r[q] = (_Float16)((k < F_IN) ? w[k * HID + col] : 0.0f);
    }
    *(half8*)(bfrag + gid * 8) = r;
}

// ---------- K6: fused MFMA GEMM + invdeg + bias + relu + layer-2 projection ----------
// 2-phase pipeline, ROLLED t-loop to keep VGPR<=64 (unified 128 incl. 64 AGPR acc):
//   STAGE(pair t+1 -> As[(t+1)&1])  issued BEFORE compute(pair t from As[t&1]);
//   one "s_waitcnt vmcnt(0); s_barrier; sched_barrier(0)" per pair.
// __launch_bounds__(512,4) forces 4 waves/EU => 2 blocks/CU (the occupancy the
// round-1 regression lost to the 128-reg quantum).
__global__ __launch_bounds__(512, 4) void gemm_fused_kernel(
        const _Float16* __restrict__ xh, const _Float16* __restrict__ aggh,
        const float* __restrict__ invdeg, const _Float16* __restrict__ bfrag,
        const float* __restrict__ b1,
        const float* __restrict__ w2l, const float* __restrict__ w2r,
        float* __restrict__ tl, float* __restrict__ tr) {
    __shared__ __attribute__((aligned(16))) _Float16 As[2][128 * 64];  // 2 x 16KB (pair buffers)
    __shared__ float tlr[128][4];
    const int tid = threadIdx.x;
    const int w = tid >> 6, lane = tid & 63;
    const int quad = lane >> 4, l15 = lane & 15;
    const int rowbase = blockIdx.x * 128;
    const int mrow0 = rowbase + (w & 1) * 64;
    const int rhalf = (w & 1) * 64;
    const int jbase = (w >> 1) * 4;

    ((float*)tlr)[tid] = 0.0f;   // 512 floats, one per thread

    // staging: thread -> (row = tid>>2, seg = (tid&3)^swz), LDS slot = tid*16B (lane-linear DMA)
    const int srow_l = tid >> 2;
    const int sseg = (tid & 3) ^ ((srow_l >> 1) & 3);
    int srow = rowbase + srow_l;
    if (srow >= N_NODES) srow = N_NODES - 1;
    const int sgoff = srow * SX + sseg * 8;        // in halfs; byte value < 77MB fits int
    const int ldst = (tid & ~63) * 16;             // byte offset of this wave's 1KB stripe

    // a-fragment LDS byte offsets (within one 8KB chunk buffer), XOR-unswizzled
    int aoff[4];
#pragma unroll
    for (int i = 0; i < 4; ++i) {
        int r = rhalf + i * 16 + l15;
        int slot = r * 4 + (quad ^ ((r >> 1) & 3));
        aoff[i] = slot * 16;
    }
    // b-fragment per-thread byte offset within bfrag
    const int boff = (jbase * 64 + lane) * 16;

    floatx4 acc[4][4];
#pragma unroll
    for (int i = 0; i < 4; ++i)
#pragma unroll
        for (int jj = 0; jj < 4; ++jj)
            acc[i][jj] = (floatx4){0.f, 0.f, 0.f, 0.f};

    auto STAGE = [&](int p) {
#pragma unroll
        for (int u = 0; u < 2; ++u) {
            const int cc = 2 * p + u;
            const _Float16* src = (cc < 6) ? aggh : xh;          // wave-uniform select
            const int kb = (cc < 6 ? cc : cc - 6) * 32;
            const _Float16* gp = src + sgoff + kb;
            char* dst = (char*)(&As[p & 1][u * 128 * 32]) + ldst;
            __builtin_amdgcn_global_load_lds(
                (const __attribute__((address_space(1))) void*)gp,
                (__attribute__((address_space(3))) void*)dst, 16, 0, 0);
        }
    };

    // ---- prologue: stage pair 0, wait, barrier ----
    STAGE(0);
    asm volatile("s_waitcnt vmcnt(0)" ::: "memory");
    __builtin_amdgcn_s_barrier();
    __builtin_amdgcn_sched_barrier(0);

#pragma unroll 1
    for (int t = 0; t < 6; ++t) {
        if (t < 5) STAGE(t + 1);                   // DMA flies under the MFMAs below
        const char* abase = (const char*)(&As[t & 1][0]);
#pragma unroll
        for (int u = 0; u < 2; ++u) {
            const int cc = 2 * t + u;
            half8 a[4], b[4];
#pragma unroll
            for (int i = 0; i < 4; ++i)
                a[i] = *(const half8*)(abase + u * 8192 + aoff[i]);
#pragma unroll
            for (int jj = 0; jj < 4; ++jj)
                b[jj] = *(const half8*)((const char*)bfrag + boff + (cc * 16 + jj) * 1024);
#pragma unroll
            for (int i = 0; i < 4; ++i)
#pragma unroll
                for (int jj = 0; jj < 4; ++jj)
                    acc[i][jj] = __builtin_amdgcn_mfma_f32_16x16x32_f16(a[i], b[jj], acc[i][jj], 0, 0, 0);
        }
        if (t == 2) {   // agg phase (cc 0..5) done: scale accumulator rows by invdeg
#pragma unroll
            for (int i = 0; i < 4; ++i) {
                int rb = mrow0 + i * 16 + quad * 4;
                floatx4 iv;
                if (rb + 3 < N_NODES) {
                    iv = *(const floatx4a*)(invdeg + rb);
                } else {
#pragma unroll
                    for (int q = 0; q < 4; ++q)
                        iv[q] = (rb + q < N_NODES) ? invdeg[rb + q] : 0.0f;
                }
#pragma unroll
                for (int jj = 0; jj < 4; ++jj)
                    acc[i][jj] *= iv;
            }
        }
        // next pair's DMA landed + all waves done reading current pair
        asm volatile("s_waitcnt vmcnt(0)" ::: "memory");
        __builtin_amdgcn_s_barrier();
        __builtin_amdgcn_sched_barrier(0);
    }

    float bb[4], wl0[4], wl1[4], wr0[4], wr1[4];
#pragma unroll
    for (int jj = 0; jj < 4; ++jj) {
        int col = (w >> 1) * 64 + jj * 16 + l15;
        bb[jj]  = b1[col];
        wl0[jj] = w2l[col * 2];  wl1[jj] = w2l[col * 2 + 1];
        wr0[jj] = w2r[col * 2];  wr1[jj] = w2r[col * 2 + 1];
    }
#pragma unroll
    for (int i = 0; i < 4; ++i) {
#pragma unroll
        for (int q = 0; q < 4; ++q) {
            float s0 = 0.f, s1 = 0.f, s2 = 0.f, s3 = 0.f;
#pragma unroll
            for (int jj = 0; jj < 4; ++jj) {
                float v = fmaxf(acc[i][jj][q] + bb[jj], 0.0f);
                s0 += v * wl0[jj]; s1 += v * wl1[jj];
                s2 += v * wr0[jj]; s3 += v * wr1[jj];
            }
#pragma unroll
            for (int m = 1; m < 16; m <<= 1) {
                s0 += __shfl_xor(s0, m, 64);
                s1 += __shfl_xor(s1, m, 64);
                s2 += __shfl_xor(s2, m, 64);
                s3 += __shfl_xor(s3, m, 64);
            }
            if (l15 == 0) {
                int rl = (w & 1) * 64 + i * 16 + quad * 4 + q;
                atomicAdd(&tlr[rl][0], s0);
                atomicAdd(&tlr[rl][1], s1);
                atomicAdd(&tlr[rl][2], s2);
                atomicAdd(&tlr[rl][3], s3);
            }
        }
    }
    __syncthreads();
    if (tid < 128) {
        int row = rowbase + tid;
        if (row < N_NODES) {
            tl[row * 2 + 0] = tlr[tid][0];
            tl[row * 2 + 1] = tlr[tid][1];
            tr[row * 2 + 0] = tlr[tid][2];
            tr[row * 2 + 1] = tlr[tid][3];
        }
    }
}

// ---------- K7: fused layer-2 gather + finalize (NO atomics) ----------
__global__ void gather_out_kernel(const int* __restrict__ row_start,
                                  const int* __restrict__ csr,
                                  const float* __restrict__ tl,
                                  const float* __restrict__ tr,
                                  const float* __restrict__ invdeg,
                                  const float* __restrict__ b2,
                                  float* __restrict__ out) {
    int i = blockIdx.x * blockDim.x + threadIdx.x;
    if (i >= N_NODES) return;
    int e0 = row_start[i], e1 = row_start[i + 1];
    float a0 = 0.f, a1 = 0.f;
    for (int e = e0; e < e1; ++e) {
        int s = csr[e];
        a0 += tl[s * 2 + 0];
        a1 += tl[s * 2 + 1];
    }
    float inv = invdeg[i];
    out[i * 2 + 0] = a0 * inv + tr[i * 2 + 0] + b2[0];
    out[i * 2 + 1] = a1 * inv + tr[i * 2 + 1] + b2[1];
}

// ---------- K8: edge_index -> f32 passthrough ----------
__global__ void cast_edges_kernel(const int* __restrict__ ei,
                                  float* __restrict__ out) {
    int i = blockIdx.x * blockDim.x + threadIdx.x;
    if (i < 2 * N_EDGES) out[i] = (float)ei[i];
}

// ---------- workspace layout (bytes) ----------
//   0          degi      800000   (memset 0)
//   800000     row_start 800016   (N+1 ints)
//   1600032    cursor    800000
//   2400032    invdeg    800000
//   3200032    csr       2000000
//   5200032    tl        1600000
//   6800032    tr        1600000
//   8400032    bsum      3200
//   8403232    boff      3200
//   8406432    bfrag     196608
//   8610000    aggh      76800000  (f16, stride SX)
//   85410000   xh        76800000  (f16, stride SX)
extern "C" void kernel_launch(void* const* d_in, const int* in_sizes, int n_in,
                              void* d_out, int out_size, void* d_ws, size_t ws_size,
                              hipStream_t stream) {
    const float* x    = (const float*)d_in[0];
    const int*   ei   = (const int*)d_in[1];
    const float* w1_l = (const float*)d_in[2];
    const float* w1_r = (const float*)d_in[3];
    const float* b1   = (const float*)d_in[4];
    const float* w2_l = (const float*)d_in[5];
    const float* w2_r = (const float*)d_in[6];
    const float* b2   = (const float*)d_in[7];

    char* ws = (char*)d_ws;
    int*   degi      = (int*)(ws);
    int*   row_start = (int*)(ws + 800000);
    int*   cursor    = (int*)(ws + 1600032);
    float* invdeg    = (float*)(ws + 2400032);
    int*   csr       = (int*)(ws + 3200032);
    float* tl        = (float*)(ws + 5200032);
    float* tr        = (float*)(ws + 6800032);
    int*   bsum      = (int*)(ws + 8400032);
    int*   boff      = (int*)(ws + 8403232);
    _Float16* bfrag  = (_Float16*)(ws + 8406432);
    _Float16* aggh   = (_Float16*)(ws + 8610000);
    _Float16* xh     = (_Float16*)(ws + 85410000);

    float* out = (float*)d_out;   // f32: logits [0,400000), edges [400000,1400000)

    (void)hipMemsetAsync(degi, 0, 800000, stream);

    cast_x_kernel<<<(N_NODES * 24) / 256, 256, 0, stream>>>(x, (half8*)xh);
    prep_bfrag_kernel<<<48, 256, 0, stream>>>(w1_l, w1_r, bfrag);

    hist_kernel<<<(N_EDGES + 255) / 256, 256, 0, stream>>>(ei, degi);
    block_sum_kernel<<<NB, 256, 0, stream>>>(degi, bsum);
    scan_bsum_kernel<<<1, 1024, 0, stream>>>(bsum, boff, row_start);
    scan_emit_kernel<<<NB, 256, 0, stream>>>(degi, boff, row_start, cursor, invdeg);
    scatter_edges_kernel<<<(N_EDGES + 255) / 256, 256, 0, stream>>>(ei, cursor, csr);

    gather_agg_kernel<<<(N_NODES * 24) / 256, 256, 0, stream>>>(
        (const half8*)xh, row_start, csr, (half8*)aggh);

    gemm_fused_kernel<<<(N_NODES + 127) / 128, 512, 0, stream>>>(
        xh, aggh, invdeg, bfrag, b1, w2_l, w2_r, tl, tr);

    gather_out_kernel<<<NB, 256, 0, stream>>>(row_start, csr, tl, tr, invdeg, b2, out);
    cast_edges_kernel<<<(2 * N_EDGES + 255) / 256, 256, 0, stream>>>(ei, out + 2 * N_NODES);
}